// Round 4
// baseline (289.794 us; speedup 1.0000x reference)
//
#include <hip/hip_runtime.h>

// Per-token head-attention: B*S tokens, each: S = Q K^T/sqrt(128) (32x32 over
// heads), P = softmax, O = P V (32x128). One wave = one token per iteration.
// Persistent waves, 4 tokens each, register-double-buffered prefetch of the
// next token's Q/K/V so ~96 loads stay in flight per wave (latency fix).

typedef __bf16 bf16x8 __attribute__((ext_vector_type(8)));
typedef __bf16 bf16x2 __attribute__((ext_vector_type(2)));
typedef float  f32x4  __attribute__((ext_vector_type(4)));

static constexpr float kScale = 0.08838834764831845f;  // 1/sqrt(128)
static constexpr int kTPW = 4;                          // tokens per wave

__device__ inline bf16x8 to_bf16x8(f32x4 a, f32x4 b) {
  bf16x8 f;
  f[0] = (__bf16)a[0]; f[1] = (__bf16)a[1];
  f[2] = (__bf16)a[2]; f[3] = (__bf16)a[3];
  f[4] = (__bf16)b[0]; f[5] = (__bf16)b[1];
  f[6] = (__bf16)b[2]; f[7] = (__bf16)b[3];
  return f;
}

__global__ __launch_bounds__(256, 2) void attn_headwise(
    const float* __restrict__ q, const float* __restrict__ k,
    const float* __restrict__ v, float* __restrict__ out, int ntok) {
  const int wave = threadIdx.x >> 6;
  const int lane = threadIdx.x & 63;
  const int lr   = lane & 15;
  const int G    = lane >> 4;
  const int NW   = gridDim.x * 4;                 // total waves
  const long wid = (long)blockIdx.x * 4 + wave;

  // P buffer: 32 rows x 20 dwords (pad: b128-aligned, ~2-way banks). 10 KB/blk.
  __shared__ __align__(16) unsigned int pbuf[4][32 * 20];
  unsigned int* pl = pbuf[wave];

  f32x4 kraw[2][4][2][2], qraw[2][4][2][2];  // [buf][kk][tile][half]
  float vraw[2][8][8];                       // [buf][dt][e]

  auto loadQK = [&](int buf, long t) {
    const float* kt = k + t * 4096;
    const float* qt = q + t * 4096;
    #pragma unroll
    for (int kk = 0; kk < 4; ++kk)
      #pragma unroll
      for (int tt = 0; tt < 2; ++tt) {
        const float* pk = kt + (16 * tt + lr) * 128 + 32 * kk + 8 * G;
        kraw[buf][kk][tt][0] = *(const f32x4*)pk;
        kraw[buf][kk][tt][1] = *(const f32x4*)(pk + 4);
        const float* pq = qt + (16 * tt + lr) * 128 + 32 * kk + 8 * G;
        qraw[buf][kk][tt][0] = *(const f32x4*)pq;
        qraw[buf][kk][tt][1] = *(const f32x4*)(pq + 4);
      }
  };
  auto loadV = [&](int buf, long t) {
    const float* vt = v + t * 4096;
    #pragma unroll
    for (int dt = 0; dt < 8; ++dt)
      #pragma unroll
      for (int e = 0; e < 8; ++e)
        vraw[buf][dt][e] = vt[(8 * G + e) * 128 + 16 * dt + lr];
  };

  long tok = wid;
  if (tok < ntok) { loadQK(0, tok); loadV(0, tok); }

  #pragma unroll
  for (int it = 0; it < kTPW; ++it) {
    const int cur = it & 1, nxt = cur ^ 1;
    const long tn = tok + NW;
    if (tok < ntok) {
      float* ot = out + tok * 4096;

      // 1) convert QK(cur) -> frags (waits only on QK loads; V still in flight)
      bf16x8 kf[4][2], qf[4][2];
      #pragma unroll
      for (int kk = 0; kk < 4; ++kk)
        #pragma unroll
        for (int tt = 0; tt < 2; ++tt) {
          kf[kk][tt] = to_bf16x8(kraw[cur][kk][tt][0], kraw[cur][kk][tt][1]);
          qf[kk][tt] = to_bf16x8(qraw[cur][kk][tt][0], qraw[cur][kk][tt][1]);
        }

      // 2) convert V(cur) -> frags
      bf16x8 vf[8];
      #pragma unroll
      for (int dt = 0; dt < 8; ++dt)
        #pragma unroll
        for (int e = 0; e < 8; ++e)
          vf[dt][e] = (__bf16)vraw[cur][dt][e];

      // 3) prefetch QK(next); pin issue point
      if (it + 1 < kTPW && tn < ntok) loadQK(nxt, tn);
      __builtin_amdgcn_sched_barrier(0);

      // 4) S^T[g][h] = sum_d K[g][d] Q[h][d]
      f32x4 acc[2][2];
      acc[0][0] = 0.f; acc[0][1] = 0.f; acc[1][0] = 0.f; acc[1][1] = 0.f;
      #pragma unroll
      for (int kk = 0; kk < 4; ++kk)
        #pragma unroll
        for (int gi = 0; gi < 2; ++gi)
          #pragma unroll
          for (int hj = 0; hj < 2; ++hj)
            acc[gi][hj] = __builtin_amdgcn_mfma_f32_16x16x32_bf16(
                kf[kk][gi], qf[kk][hj], acc[gi][hj], 0, 0, 0);

      // softmax over g (rows of S^T), per column h
      #pragma unroll
      for (int hj = 0; hj < 2; ++hj) {
        float m = acc[0][hj][0];
        #pragma unroll
        for (int gi = 0; gi < 2; ++gi)
          #pragma unroll
          for (int r = 0; r < 4; ++r) m = fmaxf(m, acc[gi][hj][r]);
        m = fmaxf(m, __shfl_xor(m, 16, 64));
        m = fmaxf(m, __shfl_xor(m, 32, 64));

        float pv[2][4];
        float s = 0.f;
        #pragma unroll
        for (int gi = 0; gi < 2; ++gi)
          #pragma unroll
          for (int r = 0; r < 4; ++r) {
            float e = __expf((acc[gi][hj][r] - m) * kScale);
            pv[gi][r] = e;
            s += e;
          }
        s += __shfl_xor(s, 16, 64);
        s += __shfl_xor(s, 32, 64);
        float inv = 1.0f / s;

        #pragma unroll
        for (int gi = 0; gi < 2; ++gi)
          #pragma unroll
          for (int mp = 0; mp < 2; ++mp) {
            bf16x2 t2;
            t2[0] = (__bf16)(pv[gi][2 * mp]     * inv);
            t2[1] = (__bf16)(pv[gi][2 * mp + 1] * inv);
            pl[(16 * hj + lr) * 20 + 8 * gi + 2 * G + mp] =
                __builtin_bit_cast(unsigned int, t2);
          }
      }

      // read P fragments (B-operand)
      bf16x8 pf[2];
      #pragma unroll
      for (int ht = 0; ht < 2; ++ht)
        pf[ht] = *(const bf16x8*)&pl[(16 * ht + lr) * 20 + 4 * G];

      // 5) prefetch V(next); pin issue point
      if (it + 1 < kTPW && tn < ntok) loadV(nxt, tn);
      __builtin_amdgcn_sched_barrier(0);

      // 6) O^T = V^T P^T ; coalesced f32x4 stores
      f32x4 zero = 0.f;
      #pragma unroll
      for (int dt = 0; dt < 8; ++dt) {
        f32x4 o0 = __builtin_amdgcn_mfma_f32_16x16x32_bf16(vf[dt], pf[0], zero, 0, 0, 0);
        f32x4 o1 = __builtin_amdgcn_mfma_f32_16x16x32_bf16(vf[dt], pf[1], zero, 0, 0, 0);
        *(f32x4*)&ot[lr * 128 + 16 * dt + 4 * G]        = o0;
        *(f32x4*)&ot[(16 + lr) * 128 + 16 * dt + 4 * G] = o1;
      }
    }
    tok = tn;
  }
}

extern "C" void kernel_launch(void* const* d_in, const int* in_sizes, int n_in,
                              void* d_out, int out_size, void* d_ws, size_t ws_size,
                              hipStream_t stream) {
  const float* q = (const float*)d_in[0];
  const float* k = (const float*)d_in[1];
  const float* v = (const float*)d_in[2];
  float* out = (float*)d_out;
  int ntok = in_sizes[0] / 4096;                       // B*S tokens
  int grid = (ntok + 4 * kTPW - 1) / (4 * kTPW);       // 4 waves/block, kTPW tokens/wave
  hipLaunchKernelGGL(attn_headwise, dim3(grid), dim3(256), 0, stream,
                     q, k, v, out, ntok);
}

// Round 5
// 117.196 us; speedup vs baseline: 2.4727x; 2.4727x over previous
//
#include <hip/hip_runtime.h>

// Per-token head-attention: B*S tokens, each: S = Q K^T/sqrt(128) (32x32 over
// heads), P = softmax over heads, O = P V (32x128).
// One wave = one token per round; persistent waves (kTPW tokens each).
// Latency fix: next token's QK loads (register, single set reused after
// convert) + V staging (global_load_lds -> double-buffered LDS, zero VGPR)
// are issued BEFORE current token's compute and kept in flight via a counted
// s_waitcnt vmcnt(48) -- never drained to 0 mid-loop (T4 pattern).

typedef __bf16 bf16x8 __attribute__((ext_vector_type(8)));
typedef __bf16 bf16x2 __attribute__((ext_vector_type(2)));
typedef float  f32x4  __attribute__((ext_vector_type(4)));

static constexpr float kScale = 0.08838834764831845f;  // 1/sqrt(128)
static constexpr int kTPW = 4;                          // tokens per wave

typedef const __attribute__((address_space(1))) unsigned int* gas_ptr;
typedef __attribute__((address_space(3))) unsigned int* las_ptr;

__device__ inline bf16x8 to_bf16x8(f32x4 a, f32x4 b) {
  bf16x8 f;
  f[0] = (__bf16)a[0]; f[1] = (__bf16)a[1];
  f[2] = (__bf16)a[2]; f[3] = (__bf16)a[3];
  f[4] = (__bf16)b[0]; f[5] = (__bf16)b[1];
  f[6] = (__bf16)b[2]; f[7] = (__bf16)b[3];
  return f;
}

__global__ __launch_bounds__(64) void attn_headwise(
    const float* __restrict__ q, const float* __restrict__ k,
    const float* __restrict__ v, float* __restrict__ out, int ntok) {
  const int lane = threadIdx.x;        // one wave per block
  const int lr   = lane & 15;
  const int G    = lane >> 4;
  const long base = (long)blockIdx.x * kTPW;

  __shared__ __align__(16) float        vbuf[2][32 * 128];  // 32 KB (f32 V, dbuf)
  __shared__ __align__(16) unsigned int pbuf[32 * 20];      // 2.5 KB (bf16 P)

  // single raw QK register set: written by issue, freed by per-kk convert+MFMA
  f32x4 kraw[4][2][2], qraw[4][2][2];

  auto clampTok = [&](long t) { return t < (long)ntok ? t : (long)ntok - 1; };

  auto issueQK = [&](long t) {
    const float* kt = k + t * 4096;
    const float* qt = q + t * 4096;
    #pragma unroll
    for (int kk = 0; kk < 4; ++kk)
      #pragma unroll
      for (int tt = 0; tt < 2; ++tt) {
        const float* pk = kt + (16 * tt + lr) * 128 + 32 * kk + 8 * G;
        kraw[kk][tt][0] = *(const f32x4*)pk;
        kraw[kk][tt][1] = *(const f32x4*)(pk + 4);
        const float* pq = qt + (16 * tt + lr) * 128 + 32 * kk + 8 * G;
        qraw[kk][tt][0] = *(const f32x4*)pq;
        qraw[kk][tt][1] = *(const f32x4*)(pq + 4);
      }
  };
  auto issueV = [&](long t, int buf) {   // fire-and-forget, no dest VGPRs
    const float* vsrc = v + t * 4096 + lane * 4;   // per-lane global source
    float*       vdst = vbuf[buf];                 // wave-uniform LDS base
    #pragma unroll
    for (int i = 0; i < 16; ++i)
      __builtin_amdgcn_global_load_lds((gas_ptr)(vsrc + i * 256),
                                       (las_ptr)(vdst + i * 256), 16, 0, 0);
  };

  // prologue: token 0's loads in flight (issue order: QK first, then V)
  issueQK(clampTok(base));
  issueV(clampTok(base), 0);

  #pragma unroll
  for (int it = 0; it < kTPW; ++it) {
    const long tok = clampTok(base + it);
    float* ot = out + tok * 4096;

    // 1) per-kk convert + QK^T MFMA (frees raw regs progressively;
    //    compiler waits vmcnt leaving V(cur) + older stores outstanding)
    f32x4 acc[2][2];
    acc[0][0] = 0.f; acc[0][1] = 0.f; acc[1][0] = 0.f; acc[1][1] = 0.f;
    #pragma unroll
    for (int kk = 0; kk < 4; ++kk) {
      bf16x8 kf[2], qf[2];
      #pragma unroll
      for (int tt = 0; tt < 2; ++tt) {
        kf[tt] = to_bf16x8(kraw[kk][tt][0], kraw[kk][tt][1]);
        qf[tt] = to_bf16x8(qraw[kk][tt][0], qraw[kk][tt][1]);
      }
      #pragma unroll
      for (int gi = 0; gi < 2; ++gi)
        #pragma unroll
        for (int hj = 0; hj < 2; ++hj)
          acc[gi][hj] = __builtin_amdgcn_mfma_f32_16x16x32_bf16(
              kf[gi], qf[hj], acc[gi][hj], 0, 0, 0);
    }

    // 2) issue NEXT token's loads (raw set now free; QK before V)
    if (it + 1 < kTPW) {
      issueQK(clampTok(base + it + 1));
      issueV(clampTok(base + it + 1), (it + 1) & 1);
    }
    __builtin_amdgcn_sched_barrier(0);

    // 3) softmax over g (rows of S^T), per column h; P -> LDS
    #pragma unroll
    for (int hj = 0; hj < 2; ++hj) {
      float m = acc[0][hj][0];
      #pragma unroll
      for (int gi = 0; gi < 2; ++gi)
        #pragma unroll
        for (int r = 0; r < 4; ++r) m = fmaxf(m, acc[gi][hj][r]);
      m = fmaxf(m, __shfl_xor(m, 16, 64));
      m = fmaxf(m, __shfl_xor(m, 32, 64));

      float pv[2][4];
      float s = 0.f;
      #pragma unroll
      for (int gi = 0; gi < 2; ++gi)
        #pragma unroll
        for (int r = 0; r < 4; ++r) {
          float e = __expf((acc[gi][hj][r] - m) * kScale);
          pv[gi][r] = e;
          s += e;
        }
      s += __shfl_xor(s, 16, 64);
      s += __shfl_xor(s, 32, 64);
      float inv = 1.0f / s;

      #pragma unroll
      for (int gi = 0; gi < 2; ++gi)
        #pragma unroll
        for (int mp = 0; mp < 2; ++mp) {
          bf16x2 t2;
          t2[0] = (__bf16)(pv[gi][2 * mp]     * inv);
          t2[1] = (__bf16)(pv[gi][2 * mp + 1] * inv);
          pbuf[(16 * hj + lr) * 20 + 8 * gi + 2 * G + mp] =
              __builtin_bit_cast(unsigned int, t2);
        }
    }
    bf16x8 pf[2];
    #pragma unroll
    for (int ht = 0; ht < 2; ++ht)
      pf[ht] = *(const bf16x8*)&pbuf[(16 * ht + lr) * 20 + 4 * G];

    // 4) counted wait: keep the 48 next-token loads (32 QK + 16 V glds)
    //    in flight; everything older (V(cur), prev stores) is drained.
    if (it + 1 < kTPW) {
      asm volatile("s_waitcnt vmcnt(48)" ::: "memory");
    } else {
      asm volatile("s_waitcnt vmcnt(0)" ::: "memory");
    }
    __builtin_amdgcn_sched_barrier(0);

    // 5) PV from LDS V(cur): O^T = V^T P^T ; coalesced f32x4 stores
    const float* vl = vbuf[it & 1];
    f32x4 zero = 0.f;
    #pragma unroll
    for (int dt = 0; dt < 8; ++dt) {
      bf16x8 vf;
      #pragma unroll
      for (int e = 0; e < 8; ++e)
        vf[e] = (__bf16)vl[(8 * G + e) * 128 + 16 * dt + lr];
      f32x4 o0 = __builtin_amdgcn_mfma_f32_16x16x32_bf16(vf, pf[0], zero, 0, 0, 0);
      f32x4 o1 = __builtin_amdgcn_mfma_f32_16x16x32_bf16(vf, pf[1], zero, 0, 0, 0);
      *(f32x4*)&ot[lr * 128 + 16 * dt + 4 * G]        = o0;
      *(f32x4*)&ot[(16 + lr) * 128 + 16 * dt + 4 * G] = o1;
    }
  }
}

extern "C" void kernel_launch(void* const* d_in, const int* in_sizes, int n_in,
                              void* d_out, int out_size, void* d_ws, size_t ws_size,
                              hipStream_t stream) {
  const float* q = (const float*)d_in[0];
  const float* k = (const float*)d_in[1];
  const float* v = (const float*)d_in[2];
  float* out = (float*)d_out;
  int ntok = in_sizes[0] / 4096;                 // B*S tokens
  int grid = (ntok + kTPW - 1) / kTPW;           // one wave per block
  hipLaunchKernelGGL(attn_headwise, dim3(grid), dim3(64), 0, stream,
                     q, k, v, out, ntok);
}